// Round 7
// baseline (13.394 us; speedup 1.0000x reference)
//
#include <hip/hip_runtime.h>
#include <math.h>

// B=8, H=W=512, N=50 pos + 50 neg clicks (from reference setup_inputs).
constexpr int B = 8, H = 512, W = 512, N = 50;
constexpr int TS = 32;                        // 32x32 pixel tile per block
constexpr int NBLOCKS = B * (H / TS) * (W / TS);   // 2048
constexpr int LCAP = 56;                      // per-class survivor capacity
constexpr float INF = 3.0e38f;

// Kernel 1 (no atomics of any scope):
//  - Per-tile exact pruning: keep q iff dmin2(q,tile) <= min_q dmax2(q,tile).
//    Retains every pixel's argmin incl. ties (pruned points strictly farther).
//  - Wave0 = pos points, wave1 = neg points (lane<50). Survivor compaction
//    via ballot+popc prefix (deterministic, parallel — replaces R6's
//    ~100-deep serialized LDS-atomic chain).
//  - score = q^2 - 2qx*x - 2qy*y (pixel-norm term dropped from BOTH classes:
//    order and ties preserved). All values exact integers in +-2^21 -> fp32
//    exact -> mask bit-exact vs reference's strict <.
//  - Per-wave loss partials (no end-of-block barrier/LDS reduction).
__global__ __launch_bounds__(256) void psl_main(
    const float* __restrict__ out,
    const int*   __restrict__ pos,
    const int*   __restrict__ neg,
    float*       __restrict__ dout,
    float*       __restrict__ partials)
{
    __shared__ float4 s_p[LCAP];
    __shared__ float4 s_n[LCAP];
    __shared__ float  s_red[4];
    __shared__ int    s_k[2];

    const int bid  = blockIdx.x;         // 0..2047
    const int t    = threadIdx.x;
    const int b    = bid >> 8;
    const int ty   = (bid >> 4) & 15;
    const int tx   = bid & 15;
    const int wave = t >> 6, lane = t & 63;

    // Points load first (waves 0,1), logits prefetch second.
    const bool isPt = (wave < 2) && (lane < N);
    int2 p;
    if (isPt) {
        const int* src = (wave == 0) ? pos : neg;
        p = ((const int2*)src)[b * N + lane];
    }

    const int r  = t >> 3;               // tile row 0..31
    const int cc = (t & 7) << 2;         // tile col base
    const int y  = ty * TS + r;
    const int x  = tx * TS + cc;
    const size_t pix = ((size_t)(b * H + y)) * W + x;
    const float4 xv = *(const float4*)(out + pix);     // 16B-aligned

    // Sentinel prefill BEFORE barrier #1 (survivor writes happen after it).
    if (t < LCAP) {
        s_p[t] = make_float4(0.0f, 0.0f, INF, 0.0f);
        s_n[t] = make_float4(0.0f, 0.0f, INF, 0.0f);
    }

    const float y0f = (float)(ty * TS), x0f = (float)(tx * TS);
    float dmin2 = INF, dmax2 = INF, c0 = 0.0f, c1 = 0.0f, c2 = 0.0f;
    if (isPt) {
        const float fy = (float)p.x, fx = (float)p.y;  // (ycoord, xcoord)
        const float yhi = y0f + 31.0f, xhi = x0f + 31.0f;
        float dy = fmaxf(fmaxf(y0f - fy, fy - yhi), 0.0f);
        float dx = fmaxf(fmaxf(x0f - fx, fx - xhi), 0.0f);
        dmin2 = dy * dy + dx * dx;                     // exact ints
        float dyM = fmaxf(fy - y0f, yhi - fy);
        float dxM = fmaxf(fx - x0f, xhi - fx);
        dmax2 = dyM * dyM + dxM * dxM;
        c0 = -2.0f * fx;
        c1 = -2.0f * fy;
        c2 = fx * fx + fy * fy;                        // < 2^20, exact
    }

    // Pruning bound = block-min of dmax2 (waves 2,3 contribute INF).
    float m = dmax2;
    #pragma unroll
    for (int off = 32; off > 0; off >>= 1)
        m = fminf(m, __shfl_down(m, off, 64));
    if (lane == 0) s_red[wave] = m;
    __syncthreads();                                   // barrier #1
    const float bound = fminf(fminf(s_red[0], s_red[1]),
                              fminf(s_red[2], s_red[3]));

    // Ballot compaction (uniform execution; deterministic lane order).
    const bool surv = isPt && (dmin2 <= bound);
    const unsigned long long bal = __ballot(surv);
    if (surv) {
        int k = __popcll(bal & ((1ull << lane) - 1ull));
        if (wave == 0) s_p[k] = make_float4(c0, c1, c2, 0.0f);
        else           s_n[k] = make_float4(c0, c1, c2, 0.0f);
    }
    if (wave < 2 && lane == 0) s_k[wave] = (int)__popcll(bal);
    __syncthreads();                                   // barrier #2
    const int K0 = (s_k[0] + 3) & ~3;
    const int K1 = (s_k[1] + 3) & ~3;

    // z-independent loss part (overlaps pixel loops).
    const float xs[4] = {xv.x, xv.y, xv.z, xv.w};
    float lsum = 0.0f;
    #pragma unroll
    for (int j = 0; j < 4; ++j)
        lsum += fmaxf(xs[j], 0.0f) + __logf(1.0f + __expf(-fabsf(xs[j])));

    // Pixel loops: 4 consecutive px per thread, pos list then neg list.
    const float yf = (float)y, xf = (float)x;
    float mp[4] = {INF, INF, INF, INF};
    float mq[4] = {INF, INF, INF, INF};
    for (int n = 0; n < K0; n += 4) {
        #pragma unroll
        for (int j = 0; j < 4; ++j) {
            float4 P = s_p[n + j];
            float cy = fmaf(P.y, yf, P.z);
            mp[0] = fminf(mp[0], fmaf(P.x, xf,        cy));
            mp[1] = fminf(mp[1], fmaf(P.x, xf + 1.0f, cy));
            mp[2] = fminf(mp[2], fmaf(P.x, xf + 2.0f, cy));
            mp[3] = fminf(mp[3], fmaf(P.x, xf + 3.0f, cy));
        }
    }
    for (int n = 0; n < K1; n += 4) {
        #pragma unroll
        for (int j = 0; j < 4; ++j) {
            float4 Q = s_n[n + j];
            float cy = fmaf(Q.y, yf, Q.z);
            mq[0] = fminf(mq[0], fmaf(Q.x, xf,        cy));
            mq[1] = fminf(mq[1], fmaf(Q.x, xf + 1.0f, cy));
            mq[2] = fminf(mq[2], fmaf(Q.x, xf + 2.0f, cy));
            mq[3] = fminf(mq[3], fmaf(Q.x, xf + 3.0f, cy));
        }
    }

    #pragma unroll
    for (int j = 0; j < 4; ++j) {
        float z = (mp[j] < mq[j]) ? 1.0f : 0.0f;       // exact ints, strict <
        dout[1 + pix + j] = z;
        lsum -= xs[j] * z;
    }

    // Per-wave deterministic reduce; no block barrier needed.
    #pragma unroll
    for (int off = 32; off > 0; off >>= 1)
        lsum += __shfl_down(lsum, off, 64);
    if (lane == 0) partials[(bid << 2) + wave] = lsum;
}

// Kernel 2: deterministic fixed-order reduction of 8192 wave partials.
// Stream ordering makes kernel-1 stores visible; no atomics.
__global__ __launch_bounds__(256) void psl_finish(
    const float* __restrict__ partials,
    float*       __restrict__ dout)
{
    __shared__ float s_red[4];
    const int t = threadIdx.x;
    float s = 0.0f;
    #pragma unroll
    for (int i = 0; i < 32; ++i)
        s += partials[t + (i << 8)];
    #pragma unroll
    for (int off = 32; off > 0; off >>= 1)
        s += __shfl_down(s, off, 64);
    if ((t & 63) == 0) s_red[t >> 6] = s;
    __syncthreads();
    if (t == 0)
        dout[0] = ((s_red[0] + s_red[1]) + (s_red[2] + s_red[3])) *
                  (1.0f / (float)(B * H * W));
}

extern "C" void kernel_launch(void* const* d_in, const int* in_sizes, int n_in,
                              void* d_out, int out_size, void* d_ws, size_t ws_size,
                              hipStream_t stream) {
    const float* out_logits = (const float*)d_in[0];
    const int*   pos        = (const int*)d_in[1];
    const int*   neg        = (const int*)d_in[2];
    float* dout     = (float*)d_out;
    float* partials = (float*)d_ws;      // 8192 floats

    psl_main<<<NBLOCKS, 256, 0, stream>>>(out_logits, pos, neg, dout, partials);
    psl_finish<<<1, 256, 0, stream>>>(partials, dout);
}

// Round 8
// 13.272 us; speedup vs baseline: 1.0091x; 1.0091x over previous
//
#include <hip/hip_runtime.h>
#include <math.h>

// B=8, H=W=512, N=50 pos + 50 neg clicks (from reference setup_inputs).
constexpr int B = 8, H = 512, W = 512, N = 50;
constexpr int TS = 32;                        // 32x32 pixel tile per block
constexpr int NBLOCKS = B * (H / TS) * (W / TS);   // 2048
constexpr int KMAX = 2 * N + 8;               // survivor capacity (+pad)
constexpr float INF = 3.0e38f;

// Kernel 1 (R6 structure; only change: ballot compaction, no LDS atomics):
//  - Per-tile exact pruning: keep q iff dmin2(q,tile) <= min_q dmax2(q,tile).
//    Retains every pixel's argmin incl. ties (pruned points strictly farther).
//  - Combined pos/neg parity stream: score = 2*d2 + tag (pos=1), pixel-norm
//    term dropped (even -> order & parity preserved). Parity of signed-int
//    min == reference's strict-< mask. Exact integers in +-2^22 -> fp32
//    exact -> bit-exact mask.
//  - Survivor compaction: wave0 owns pos, wave1 owns neg (lane<50);
//    position = popc(ballot & below) with neg offset by wave0's count.
//    Deterministic, parallel — replaces the ~100-deep LDS-atomic chain.
__global__ __launch_bounds__(256) void psl_main(
    const float* __restrict__ out,
    const int*   __restrict__ pos,
    const int*   __restrict__ neg,
    float*       __restrict__ dout,
    float*       __restrict__ partials)
{
    __shared__ float4 s_pts[KMAX];
    __shared__ float  s_red[4];
    __shared__ int    s_k0;

    const int bid  = blockIdx.x;         // 0..2047
    const int t    = threadIdx.x;
    const int b    = bid >> 8;           // 256 tiles per batch
    const int ty   = (bid >> 4) & 15;
    const int tx   = bid & 15;
    const int wave = t >> 6, lane = t & 63;

    // Logits prefetch at entry (hides under prologue).
    const int r  = t >> 3;               // tile row 0..31
    const int cc = (t & 7) << 2;         // tile col base
    const int y  = ty * TS + r;
    const int x  = tx * TS + cc;
    const size_t pix = ((size_t)(b * H + y)) * W + x;
    const float4 xv = *(const float4*)(out + pix);     // 16B-aligned

    // Sentinel prefill BEFORE barrier #1.
    if (t < KMAX) s_pts[t] = make_float4(0.0f, 0.0f, INF, 0.0f);

    const float y0f = (float)(ty * TS), x0f = (float)(tx * TS);
    const bool isPt = (wave < 2) && (lane < N);
    float dmin2 = INF, dmax2 = INF, c0 = 0.0f, c1 = 0.0f, c2 = 0.0f;
    if (isPt) {
        const int* src = (wave == 0) ? pos : neg;
        int2 p = ((const int2*)src)[b * N + lane];
        const float fy = (float)p.x, fx = (float)p.y;  // (ycoord, xcoord)
        const float tag = (wave == 0) ? 1.0f : 0.0f;
        const float yhi = y0f + 31.0f, xhi = x0f + 31.0f;
        float dy = fmaxf(fmaxf(y0f - fy, fy - yhi), 0.0f);
        float dx = fmaxf(fmaxf(x0f - fx, fx - xhi), 0.0f);
        dmin2 = dy * dy + dx * dx;                     // exact ints
        float dyM = fmaxf(fy - y0f, yhi - fy);
        float dxM = fmaxf(fx - x0f, xhi - fx);
        dmax2 = dyM * dyM + dxM * dxM;
        c0 = -4.0f * fx;
        c1 = -4.0f * fy;
        c2 = 2.0f * (fx * fx + fy * fy) + tag;         // < 2^21, exact
    }

    // Pruning bound = block-min of dmax2 (waves 2,3 contribute INF).
    float m = dmax2;
    #pragma unroll
    for (int off = 32; off > 0; off >>= 1)
        m = fminf(m, __shfl_down(m, off, 64));
    if (lane == 0) s_red[wave] = m;
    __syncthreads();                                   // barrier #1
    const float bound = fminf(fminf(s_red[0], s_red[1]),
                              fminf(s_red[2], s_red[3]));

    // Ballot compaction into ONE combined list (pos block, then neg block).
    const bool surv = isPt && (dmin2 <= bound);
    const unsigned long long bal = __ballot(surv);
    if (wave == 0 && lane == 0) s_k0 = (int)__popcll(bal);
    __syncthreads();                                   // barrier #2 (k0 ready)
    if (surv) {
        int k = __popcll(bal & ((1ull << lane) - 1ull));
        if (wave == 1) k += s_k0;
        s_pts[k] = make_float4(c0, c1, c2, 0.0f);
    }
    if (wave == 1 && lane == 0) s_k0 += (int)__popcll(bal);  // total count
    __syncthreads();                                   // barrier #3
    const int K = (s_k0 + 3) & ~3;                     // sentinel-padded

    // z-independent loss part (overlaps pixel loop).
    const float xs[4] = {xv.x, xv.y, xv.z, xv.w};
    float lsum = 0.0f;
    #pragma unroll
    for (int j = 0; j < 4; ++j)
        lsum += fmaxf(xs[j], 0.0f) + __logf(1.0f + __expf(-fabsf(xs[j])));

    // Pixel loop: 4 consecutive px per thread over the combined list.
    const float yf = (float)y, xf = (float)x;
    float mn[4] = {INF, INF, INF, INF};
    for (int n = 0; n < K; n += 4) {
        #pragma unroll
        for (int j = 0; j < 4; ++j) {
            float4 P = s_pts[n + j];
            float cy = fmaf(P.y, yf, P.z);
            mn[0] = fminf(mn[0], fmaf(P.x, xf,        cy));
            mn[1] = fminf(mn[1], fmaf(P.x, xf + 1.0f, cy));
            mn[2] = fminf(mn[2], fmaf(P.x, xf + 2.0f, cy));
            mn[3] = fminf(mn[3], fmaf(P.x, xf + 3.0f, cy));
        }
    }

    #pragma unroll
    for (int j = 0; j < 4; ++j) {
        int mi = (int)mn[j];                        // exact signed int
        float z = (float)(mi & 1);                  // parity -> mask
        dout[1 + pix + j] = z;
        lsum -= xs[j] * z;
    }

    // Deterministic block reduction of loss.
    #pragma unroll
    for (int off = 32; off > 0; off >>= 1)
        lsum += __shfl_down(lsum, off, 64);
    __syncthreads();                     // s_red reuse safe
    if (lane == 0) s_red[wave] = lsum;
    __syncthreads();
    if (t == 0)
        partials[bid] = (s_red[0] + s_red[1]) + (s_red[2] + s_red[3]);
}

// Kernel 2: deterministic final reduction of 2048 block partials -> mean.
// Stream ordering makes kernel-1 stores visible; no atomics needed.
__global__ __launch_bounds__(256) void psl_finish(
    const float* __restrict__ partials,
    float*       __restrict__ dout)
{
    __shared__ float s_red[4];
    const int t = threadIdx.x;
    float s = ((partials[t]        + partials[t + 256]) +
               (partials[t + 512]  + partials[t + 768])) +
              ((partials[t + 1024] + partials[t + 1280]) +
               (partials[t + 1536] + partials[t + 1792]));
    #pragma unroll
    for (int off = 32; off > 0; off >>= 1)
        s += __shfl_down(s, off, 64);
    if ((t & 63) == 0) s_red[t >> 6] = s;
    __syncthreads();
    if (t == 0)
        dout[0] = ((s_red[0] + s_red[1]) + (s_red[2] + s_red[3])) *
                  (1.0f / (float)(B * H * W));
}

extern "C" void kernel_launch(void* const* d_in, const int* in_sizes, int n_in,
                              void* d_out, int out_size, void* d_ws, size_t ws_size,
                              hipStream_t stream) {
    const float* out_logits = (const float*)d_in[0];
    const int*   pos        = (const int*)d_in[1];
    const int*   neg        = (const int*)d_in[2];
    float* dout     = (float*)d_out;
    float* partials = (float*)d_ws;      // 2048 floats

    psl_main<<<NBLOCKS, 256, 0, stream>>>(out_logits, pos, neg, dout, partials);
    psl_finish<<<1, 256, 0, stream>>>(partials, dout);
}